// Round 1
// baseline (632.714 us; speedup 1.0000x reference)
//
#include <hip/hip_runtime.h>
#include <cmath>

// FlowmatchingActionHead forward, fp32 baseline.
// Inputs (setup_inputs order):
//  0 actions   (4096, 64)  f32
//  1 timesteps (128,)      i32
//  2 cat_ids   (4096,)     i32
//  3 W1 (8, 64, 1024) f32    4 b1 (8,1024) f32
//  5 W2 (8, 2048,1024) f32   6 b2 (8,1024) f32
//  7 W3 (8, 1024,1024) f32   8 b3 (8,1024) f32
// out: (4096, 1024) f32
//
// Plan: bucket tokens by cat (perm + cat_off), precompute tau[128][1024],
// then three tiled fp32 GEMMs (BM=BN=64, BK=16, 256 thr, 4x4 microtile).
// Intermediates stored GROUPED by cat so only GEMM1 gathers (actions) and
// GEMM3 scatters (d_out); GEMM2 reads grouped rows + tau via perm%128.
// ws usage: ~33.5 MiB.

#define NTOK 4096
#define AD   64
#define HID  1024
#define NC   8
#define NB   128

__global__ void build_perm_kernel(const int* __restrict__ cat,
                                  int* __restrict__ perm,
                                  int* __restrict__ cat_off) {
  __shared__ int cnt[NC];
  __shared__ int off[NC + 1];
  const int tid = threadIdx.x;
  if (tid < NC) cnt[tid] = 0;
  __syncthreads();
  for (int n = tid; n < NTOK; n += blockDim.x) atomicAdd(&cnt[cat[n]], 1);
  __syncthreads();
  if (tid == 0) {
    int s = 0;
    for (int c = 0; c < NC; ++c) { off[c] = s; s += cnt[c]; }
    off[NC] = s;
  }
  __syncthreads();
  if (tid < NC) cnt[tid] = off[tid];          // reuse as per-cat cursor
  if (tid <= NC) cat_off[tid] = off[tid];
  __syncthreads();
  for (int n = tid; n < NTOK; n += blockDim.x) {
    int pos = atomicAdd(&cnt[cat[n]], 1);
    perm[pos] = n;                            // order within cat irrelevant
  }
}

// tau[b][2i] = sin(t_b * div_i), tau[b][2i+1] = cos(t_b * div_i)
// div_i = exp(i * (-ln(10000)/512))   (scalar computed in f64 like numpy)
__global__ void tau_kernel(const int* __restrict__ ts, float* __restrict__ tau) {
  const int b = blockIdx.x;                   // 0..127
  const float t = (float)ts[b];
  const float cdiv = -0.017988946009362652f;  // -log(10000.0)/512 (f64 -> f32)
  for (int i = threadIdx.x; i < HID / 2; i += blockDim.x) {
    float div = expf(cdiv * (float)i);
    float ang = t * div;
    tau[(size_t)b * HID + 2 * i]     = sinf(ang);
    tau[(size_t)b * HID + 2 * i + 1] = cosf(ang);
  }
}

// MODE 0: A = actions gathered via perm (K=64),  out = aemb (grouped), bias b1
// MODE 1: A = [aemb | tau] (K=2048),             out = h    (grouped), bias b2, SiLU
// MODE 2: A = h (grouped)  (K=1024),             out = d_out scattered, bias b3
template <int K, int MODE>
__global__ __launch_bounds__(256, 4) void cat_gemm_kernel(
    const float* __restrict__ A0, const float* __restrict__ Tau,
    const float* __restrict__ W, const float* __restrict__ Bias,
    const int* __restrict__ perm, const int* __restrict__ cat_off,
    float* __restrict__ Out) {
  constexpr int BM = 64, BN = 64, BK = 16;
  const int c   = blockIdx.z;
  const int g0  = cat_off[c];
  const int cnt = cat_off[c + 1] - g0;
  const int m0  = blockIdx.y * BM;
  if (m0 >= cnt) return;                      // spare m-tiles exit fast
  const int n0  = blockIdx.x * BN;

  __shared__ float As[BK][BM + 4];            // +4 pad: conflict-free transposed store
  __shared__ float Bs[BK][BN];
  __shared__ int   rows[BM];

  const int tid = threadIdx.x;
  if (tid < BM) {
    int m = m0 + tid;
    if (m > cnt - 1) m = cnt - 1;             // clamp tail rows
    rows[tid] = perm[g0 + m];
  }
  __syncthreads();

  const int ar = tid >> 2;                    // A-stage row  (0..63)
  const int as = (tid & 3) * 4;               // A-stage col seg
  const int br = tid >> 4;                    // B-stage row  (0..15)
  const int bs = (tid & 15) * 4;              // B-stage col seg
  const int tx = tid & 15;                    // microtile col group
  const int ty = tid >> 4;                    // microtile row group

  const float* __restrict__ Wc = W + (size_t)c * K * HID + n0;

  int gm = m0 + ar;
  if (gm > cnt - 1) gm = cnt - 1;
  const float* aptr;
  const float* tptr = nullptr;
  if (MODE == 0) aptr = A0 + (size_t)rows[ar] * AD;
  else           aptr = A0 + (size_t)(g0 + gm) * HID;
  if (MODE == 1) tptr = Tau + (size_t)(rows[ar] & (NB - 1)) * HID - HID;

  float acc[4][4] = {};

  for (int kt = 0; kt < K; kt += BK) {
    const int col = kt + as;
    float4 av;
    if (MODE == 1) {
      av = (col < HID) ? *(const float4*)(aptr + col)
                       : *(const float4*)(tptr + col);  // tptr pre-shifted by -HID
    } else {
      av = *(const float4*)(aptr + col);
    }
    const float4 bv = *(const float4*)(Wc + (size_t)(kt + br) * HID + bs);

    As[as + 0][ar] = av.x;
    As[as + 1][ar] = av.y;
    As[as + 2][ar] = av.z;
    As[as + 3][ar] = av.w;
    *(float4*)&Bs[br][bs] = bv;
    __syncthreads();

#pragma unroll
    for (int k = 0; k < BK; ++k) {
      const float4 a4 = *(const float4*)&As[k][ty * 4];
      const float4 b4 = *(const float4*)&Bs[k][tx * 4];
      const float a[4] = {a4.x, a4.y, a4.z, a4.w};
      const float b[4] = {b4.x, b4.y, b4.z, b4.w};
#pragma unroll
      for (int i = 0; i < 4; ++i)
#pragma unroll
        for (int j = 0; j < 4; ++j)
          acc[i][j] = fmaf(a[i], b[j], acc[i][j]);
    }
    __syncthreads();
  }

  const float4 bias4 = *(const float4*)(Bias + (size_t)c * HID + n0 + tx * 4);
  const float bb[4] = {bias4.x, bias4.y, bias4.z, bias4.w};

#pragma unroll
  for (int i = 0; i < 4; ++i) {
    const int m = m0 + ty * 4 + i;
    if (m >= cnt) continue;
    float r[4];
#pragma unroll
    for (int j = 0; j < 4; ++j) {
      float v = acc[i][j] + bb[j];
      if (MODE == 1) v = v / (1.0f + expf(-v));   // SiLU
      r[j] = v;
    }
    float* dst;
    if (MODE == 2) dst = Out + (size_t)rows[ty * 4 + i] * HID + n0 + tx * 4;
    else           dst = Out + (size_t)(g0 + m) * HID + n0 + tx * 4;
    *(float4*)dst = make_float4(r[0], r[1], r[2], r[3]);
  }
}

extern "C" void kernel_launch(void* const* d_in, const int* in_sizes, int n_in,
                              void* d_out, int out_size, void* d_ws, size_t ws_size,
                              hipStream_t stream) {
  const float* actions   = (const float*)d_in[0];
  const int*   timesteps = (const int*)d_in[1];
  const int*   cat_ids   = (const int*)d_in[2];
  const float* W1 = (const float*)d_in[3];
  const float* b1 = (const float*)d_in[4];
  const float* W2 = (const float*)d_in[5];
  const float* b2 = (const float*)d_in[6];
  const float* W3 = (const float*)d_in[7];
  const float* b3 = (const float*)d_in[8];
  float* out = (float*)d_out;

  char* ws = (char*)d_ws;
  int*   perm    = (int*)ws;                          // 16 KiB
  int*   cat_off = (int*)(ws + 16384);                // 64 B
  float* tau     = (float*)(ws + 65536);              // 512 KiB
  float* aemb    = (float*)(ws + (1u << 20));         // 16 MiB (grouped)
  float* h       = (float*)(ws + (17u << 20));        // 16 MiB (grouped)

  build_perm_kernel<<<1, 256, 0, stream>>>(cat_ids, perm, cat_off);
  tau_kernel<<<NB, 256, 0, stream>>>(timesteps, tau);

  // grid: x = N tiles (1024/64), y = worst-case M tiles per cat, z = cats
  dim3 grid(HID / 64, NTOK / 64, NC);
  cat_gemm_kernel<AD, 0><<<grid, 256, 0, stream>>>(actions, nullptr, W1, b1,
                                                   perm, cat_off, aemb);
  cat_gemm_kernel<2 * HID, 1><<<grid, 256, 0, stream>>>(aemb, tau, W2, b2,
                                                        perm, cat_off, h);
  cat_gemm_kernel<HID, 2><<<grid, 256, 0, stream>>>(h, nullptr, W3, b3,
                                                    perm, cat_off, out);
}

// Round 3
// 279.318 us; speedup vs baseline: 2.2652x; 2.2652x over previous
//
#include <hip/hip_runtime.h>
#include <cmath>

// FlowmatchingActionHead forward — fp16-input MFMA, fp32 accumulate.
// Pipeline: perm/tau/gather/W-transpose prep (fp16), then 3 MFMA GEMMs
// (128x128 tile, BK=32, 8 waves, double-buffered LDS, global_load_lds x16).
// ws: contiguous ~75.5 MiB.

#define NTOK 4096
#define HID  1024
#define NC   8
#define MPAD 4224  // grouped rows padded so tile staging never reads OOB

typedef _Float16 f16;
typedef _Float16 f16x8 __attribute__((ext_vector_type(8)));
typedef float    f32x4 __attribute__((ext_vector_type(4)));

#define GLDS16(g, l) __builtin_amdgcn_global_load_lds(                      \
    (const __attribute__((address_space(1))) void*)(g),                     \
    (__attribute__((address_space(3))) void*)(l), 16, 0, 0)

__global__ void build_perm_kernel(const int* __restrict__ cat,
                                  int* __restrict__ perm,
                                  int* __restrict__ cat_off) {
  __shared__ int cnt[NC];
  __shared__ int off[NC + 1];
  const int tid = threadIdx.x;
  if (tid < NC) cnt[tid] = 0;
  __syncthreads();
  for (int n = tid; n < NTOK; n += blockDim.x) atomicAdd(&cnt[cat[n]], 1);
  __syncthreads();
  if (tid == 0) {
    int s = 0;
    for (int c = 0; c < NC; ++c) { off[c] = s; s += cnt[c]; }
    off[NC] = s;
  }
  __syncthreads();
  if (tid < NC) cnt[tid] = off[tid];
  if (tid <= NC) cat_off[tid] = off[tid];
  __syncthreads();
  for (int n = tid; n < NTOK; n += blockDim.x) {
    int pos = atomicAdd(&cnt[cat[n]], 1);
    perm[pos] = n;
  }
}

// tau16[b][2i]=sin(t*div_i), [2i+1]=cos; div_i=exp(i * -ln(1e4)/512)
__global__ void tau16_kernel(const int* __restrict__ ts, f16* __restrict__ tau) {
  const int b = blockIdx.x;
  const float t = (float)ts[b];
  const float cdiv = -0.017988946039015984f;  // -log(10000.0)/512
  for (int i = threadIdx.x; i < HID / 2; i += blockDim.x) {
    float ang = t * expf(cdiv * (float)i);
    tau[(size_t)b * HID + 2 * i]     = (f16)sinf(ang);
    tau[(size_t)b * HID + 2 * i + 1] = (f16)cosf(ang);
  }
}

// Per grouped row r: gather actions -> act_g (fp16) and tau row -> xcat[:,1024:]
__global__ void gather_kernel(const float* __restrict__ actions,
                              const f16* __restrict__ tau,
                              const int* __restrict__ perm,
                              f16* __restrict__ act_g, f16* __restrict__ xcat) {
  const int r = blockIdx.x;
  const int tok = perm[r];
  const int t = threadIdx.x;  // 128 threads
  if (t < 64) act_g[(size_t)r * 64 + t] = (f16)actions[(size_t)tok * 64 + t];
  const uint4* src = (const uint4*)(tau + (size_t)(tok & 127) * HID);
  uint4* dst = (uint4*)(xcat + (size_t)r * 2048 + HID);
  dst[t] = src[t];  // 128 x 16B = 2048 B = 1024 fp16
}

// W (NC,K,HID) f32 -> Wt (NC,HID,K) f16, 64x64 LDS-tiled transpose
__global__ __launch_bounds__(256) void wcvt_kernel(const float* __restrict__ W,
                                                   f16* __restrict__ Wt, int K) {
  const int c = blockIdx.z, k0 = blockIdx.y * 64, n0 = blockIdx.x * 64;
  __shared__ f16 tl[64][68];
  const int tid = threadIdx.x;
  const int rr = tid >> 4, cs = (tid & 15) * 4;
  const float* src = W + ((size_t)c * K + k0) * HID + n0;
#pragma unroll
  for (int it = 0; it < 4; ++it) {
    const int kr = rr + it * 16;
    float4 v = *(const float4*)(src + (size_t)kr * HID + cs);
    tl[kr][cs + 0] = (f16)v.x;
    tl[kr][cs + 1] = (f16)v.y;
    tl[kr][cs + 2] = (f16)v.z;
    tl[kr][cs + 3] = (f16)v.w;
  }
  __syncthreads();
  f16* dst = Wt + ((size_t)c * HID + n0) * K + k0;
#pragma unroll
  for (int it = 0; it < 4; ++it) {
    const int nr = rr + it * 16;
    union { f16 h[4]; uint2 u; } pk;
    pk.h[0] = tl[cs + 0][nr];
    pk.h[1] = tl[cs + 1][nr];
    pk.h[2] = tl[cs + 2][nr];
    pk.h[3] = tl[cs + 3][nr];
    *(uint2*)(dst + (size_t)nr * K + cs) = pk.u;
  }
}

// MODE 0: A=act_g (K=64)    -> xcat[:, :1024] (pitch 2048, fp16), +b1
// MODE 1: A=xcat  (K=2048)  -> h (pitch 1024, fp16), +b2, SiLU
// MODE 2: A=h     (K=1024)  -> d_out scattered via perm (pitch 1024, f32), +b3
template <int K, int MODE>
__global__ __launch_bounds__(512) void mfma_gemm(
    const f16* __restrict__ A, const f16* __restrict__ Wt,
    const float* __restrict__ Bias, const int* __restrict__ perm,
    const int* __restrict__ cat_off, void* __restrict__ OutV) {
  constexpr int PA = (MODE == 0) ? 64 : (MODE == 1) ? 2048 : 1024;
  constexpr int NT = K / 32;
  const int c = blockIdx.z;
  const int g0 = cat_off[c], cnt = cat_off[c + 1] - g0;
  const int m0 = blockIdx.y * 128;
  if (m0 >= cnt) return;
  const int n0 = blockIdx.x * 128;

  __shared__ f16 As[2][4096];  // [buf][128 rows x 32 k]
  __shared__ f16 Bs[2][4096];  // [buf][128 cols x 32 k]
  __shared__ int rows[128];

  const int tid = threadIdx.x;
  const int lane = tid & 63, wid = tid >> 6;

  if (MODE == 2 && tid < 128) {
    int m = m0 + tid;
    if (m > cnt - 1) m = cnt - 1;
    rows[tid] = perm[g0 + m];
  }

  const f16* Abase = A + (size_t)(g0 + m0) * PA;
  const f16* Bbase = Wt + ((size_t)c * HID + n0) * K;
  const int srow = tid >> 2, sks = (tid & 3) * 8;

  f32x4 acc[2][4];
#pragma unroll
  for (int i = 0; i < 2; ++i)
#pragma unroll
    for (int j = 0; j < 4; ++j) acc[i][j] = (f32x4){0.f, 0.f, 0.f, 0.f};

  const int wm = wid >> 1, wn = wid & 1;  // 4 m-groups x 2 n-groups
  const int fr = lane & 15, fk = (lane >> 4) * 8;

#define STAGE(buf, kt)                                                \
  do {                                                                \
    GLDS16(Abase + (size_t)srow * PA + (kt) + sks, &As[buf][tid * 8]); \
    GLDS16(Bbase + (size_t)srow * K + (kt) + sks, &Bs[buf][tid * 8]);  \
  } while (0)

  STAGE(0, 0);
  __syncthreads();
  int cur = 0;
  for (int t = 0; t < NT; ++t) {
    if (t + 1 < NT) STAGE(cur ^ 1, (t + 1) * 32);  // prefetch in flight over MFMA
    f16x8 a[2], b[4];
#pragma unroll
    for (int i = 0; i < 2; ++i)
      a[i] = *(const f16x8*)&As[cur][(wm * 32 + i * 16 + fr) * 32 + fk];
#pragma unroll
    for (int j = 0; j < 4; ++j)
      b[j] = *(const f16x8*)&Bs[cur][(wn * 64 + j * 16 + fr) * 32 + fk];
#pragma unroll
    for (int i = 0; i < 2; ++i)
#pragma unroll
      for (int j = 0; j < 4; ++j)
        acc[i][j] = __builtin_amdgcn_mfma_f32_16x16x32_f16(a[i], b[j], acc[i][j], 0, 0, 0);
    __syncthreads();  // drains prefetch (vmcnt) + guards LDS reuse (lgkm)
    cur ^= 1;
  }
#undef STAGE

#pragma unroll
  for (int i = 0; i < 2; ++i) {
    const int mlbase = wm * 32 + i * 16 + (lane >> 4) * 4;
#pragma unroll
    for (int j = 0; j < 4; ++j) {
      const int col = wn * 64 + j * 16 + fr;  // C/D: col=lane&15, row=(lane>>4)*4+q
      const float bb = Bias[c * HID + n0 + col];
#pragma unroll
      for (int q = 0; q < 4; ++q) {
        const int ml = mlbase + q;
        if (m0 + ml >= cnt) continue;
        float v = acc[i][j][q] + bb;
        if (MODE == 1) v = v / (1.0f + __expf(-v));
        if (MODE == 2) {
          ((float*)OutV)[(size_t)rows[ml] * HID + n0 + col] = v;
        } else if (MODE == 1) {
          ((f16*)OutV)[(size_t)(g0 + m0 + ml) * HID + n0 + col] = (f16)v;
        } else {
          ((f16*)OutV)[(size_t)(g0 + m0 + ml) * 2048 + n0 + col] = (f16)v;
        }
      }
    }
  }
}

extern "C" void kernel_launch(void* const* d_in, const int* in_sizes, int n_in,
                              void* d_out, int out_size, void* d_ws, size_t ws_size,
                              hipStream_t stream) {
  const float* actions   = (const float*)d_in[0];
  const int*   timesteps = (const int*)d_in[1];
  const int*   cat_ids   = (const int*)d_in[2];
  const float* W1 = (const float*)d_in[3];
  const float* b1 = (const float*)d_in[4];
  const float* W2 = (const float*)d_in[5];
  const float* b2 = (const float*)d_in[6];
  const float* W3 = (const float*)d_in[7];
  const float* b3 = (const float*)d_in[8];
  float* out = (float*)d_out;

  // Compact contiguous ws layout (~75.5 MiB total).
  char* ws = (char*)d_ws;
  const size_t MiB = 1u << 20;
  int* perm    = (int*)(ws + 0);                       // 16 KiB
  int* cat_off = (int*)(ws + (16u << 10));             // 36 B
  f16* tau16   = (f16*)(ws + (32u << 10));             // 256 KiB
  f16* act_g   = (f16*)(ws + (512u << 10));            // 528 KiB (MPAD x 64)
  f16* Wt1     = (f16*)(ws + 2 * MiB);                 // 1 MiB   (8,1024,64)
  f16* xcat    = (f16*)(ws + 3 * MiB);                 // 16.5 MiB (MPAD x 2048)
  f16* h       = (f16*)(ws + 20 * MiB);                // 8.25 MiB (MPAD x 1024)
  f16* Wt2     = (f16*)(ws + 29 * MiB);                // 32 MiB  (8,1024,2048)
  f16* Wt3     = (f16*)(ws + 61 * MiB);                // 16 MiB  (8,1024,1024)  -> ends 77 MiB

  build_perm_kernel<<<1, 256, 0, stream>>>(cat_ids, perm, cat_off);
  tau16_kernel<<<128, 256, 0, stream>>>(timesteps, tau16);
  gather_kernel<<<NTOK, 128, 0, stream>>>(actions, tau16, perm, act_g, xcat);

  wcvt_kernel<<<dim3(HID / 64, 1, NC), 256, 0, stream>>>(W1, Wt1, 64);
  wcvt_kernel<<<dim3(HID / 64, 32, NC), 256, 0, stream>>>(W2, Wt2, 2048);
  wcvt_kernel<<<dim3(HID / 64, 16, NC), 256, 0, stream>>>(W3, Wt3, 1024);

  dim3 ggrid(HID / 128, NTOK / 128, NC);
  mfma_gemm<64, 0><<<ggrid, 512, 0, stream>>>(act_g, Wt1, b1, perm, cat_off, xcat);
  mfma_gemm<2048, 1><<<ggrid, 512, 0, stream>>>(xcat, Wt2, b2, perm, cat_off, h);
  mfma_gemm<1024, 2><<<ggrid, 512, 0, stream>>>(h, Wt3, b3, perm, cat_off, out);
}

// Round 4
// 262.008 us; speedup vs baseline: 2.4149x; 1.0661x over previous
//
#include <hip/hip_runtime.h>
#include <cmath>

// FlowmatchingActionHead forward — fp16 MFMA, fp32 accumulate.
// R4: BM=64 tiles via device tile-map (2+ blocks/CU), BK=64, 3-deep LDS
// buffering with counted vmcnt (never drains to 0 in-loop), XOR bank swizzle
// (inverse-swizzled global src for global_load_lds + swizzled ds_read).

#define NTOK 4096
#define HID  1024
#define NC   8
#define MPAD 4224  // grouped rows padded so tile staging never reads OOB

typedef _Float16 f16;
typedef _Float16 f16x8 __attribute__((ext_vector_type(8)));
typedef float    f32x4 __attribute__((ext_vector_type(4)));

#define GLDS16(g, l) __builtin_amdgcn_global_load_lds(                      \
    (const __attribute__((address_space(1))) void*)(g),                     \
    (__attribute__((address_space(3))) void*)(l), 16, 0, 0)
#define WAITV(n) asm volatile("s_waitcnt vmcnt(" #n ")" ::: "memory")

__global__ void build_perm_kernel(const int* __restrict__ cat,
                                  int* __restrict__ perm,
                                  int* __restrict__ cat_off,
                                  int* __restrict__ tmap) {
  __shared__ int cnt[NC];
  __shared__ int off[NC + 1];
  const int tid = threadIdx.x;
  if (tid < NC) cnt[tid] = 0;
  __syncthreads();
  for (int n = tid; n < NTOK; n += blockDim.x) atomicAdd(&cnt[cat[n]], 1);
  __syncthreads();
  if (tid == 0) {
    int s = 0;
    for (int c = 0; c < NC; ++c) { off[c] = s; s += cnt[c]; }
    off[NC] = s;
    // tile map: slots of (cat, m0) with BM=64
    int ns = 0;
    for (int c = 0; c < NC; ++c) {
      const int n = off[c + 1] - off[c];
      for (int m0 = 0; m0 < n; m0 += 64) tmap[1 + ns++] = (c << 20) | m0;
    }
    tmap[0] = ns;
  }
  __syncthreads();
  if (tid < NC) cnt[tid] = off[tid];
  if (tid <= NC) cat_off[tid] = off[tid];
  __syncthreads();
  for (int n = tid; n < NTOK; n += blockDim.x) {
    int pos = atomicAdd(&cnt[cat[n]], 1);
    perm[pos] = n;
  }
}

// tau16[b][2i]=sin(t*div_i), [2i+1]=cos; div_i=exp(i * -ln(1e4)/512)
__global__ void tau16_kernel(const int* __restrict__ ts, f16* __restrict__ tau) {
  const int b = blockIdx.x;
  const float t = (float)ts[b];
  const float cdiv = -0.017988946039015984f;  // -log(10000.0)/512
  for (int i = threadIdx.x; i < HID / 2; i += blockDim.x) {
    float ang = t * expf(cdiv * (float)i);
    tau[(size_t)b * HID + 2 * i]     = (f16)sinf(ang);
    tau[(size_t)b * HID + 2 * i + 1] = (f16)cosf(ang);
  }
}

// Per grouped row r: gather actions -> act_g (fp16) and tau row -> xcat[:,1024:]
__global__ void gather_kernel(const float* __restrict__ actions,
                              const f16* __restrict__ tau,
                              const int* __restrict__ perm,
                              f16* __restrict__ act_g, f16* __restrict__ xcat) {
  const int r = blockIdx.x;
  const int tok = perm[r];
  const int t = threadIdx.x;  // 128 threads
  if (t < 64) act_g[(size_t)r * 64 + t] = (f16)actions[(size_t)tok * 64 + t];
  const uint4* src = (const uint4*)(tau + (size_t)(tok & 127) * HID);
  uint4* dst = (uint4*)(xcat + (size_t)r * 2048 + HID);
  dst[t] = src[t];  // 128 x 16B = 1024 fp16
}

// W (NC,K,HID) f32 -> Wt (NC,HID,K) f16, 64x64 LDS-tiled transpose
__global__ __launch_bounds__(256) void wcvt_kernel(const float* __restrict__ W,
                                                   f16* __restrict__ Wt, int K) {
  const int c = blockIdx.z, k0 = blockIdx.y * 64, n0 = blockIdx.x * 64;
  __shared__ f16 tl[64][68];
  const int tid = threadIdx.x;
  const int rr = tid >> 4, cs = (tid & 15) * 4;
  const float* src = W + ((size_t)c * K + k0) * HID + n0;
#pragma unroll
  for (int it = 0; it < 4; ++it) {
    const int kr = rr + it * 16;
    float4 v = *(const float4*)(src + (size_t)kr * HID + cs);
    tl[kr][cs + 0] = (f16)v.x;
    tl[kr][cs + 1] = (f16)v.y;
    tl[kr][cs + 2] = (f16)v.z;
    tl[kr][cs + 3] = (f16)v.w;
  }
  __syncthreads();
  f16* dst = Wt + ((size_t)c * HID + n0) * K + k0;
#pragma unroll
  for (int it = 0; it < 4; ++it) {
    const int nr = rr + it * 16;
    union { f16 h[4]; uint2 u; } pk;
    pk.h[0] = tl[cs + 0][nr];
    pk.h[1] = tl[cs + 1][nr];
    pk.h[2] = tl[cs + 2][nr];
    pk.h[3] = tl[cs + 3][nr];
    *(uint2*)(dst + (size_t)nr * K + cs) = pk.u;
  }
}

// Tile: BM=64, BN=128, BK=64. 4 waves (2m x 2n), wave tile 32x64.
// MODE 0: A=act_g (K=64)   -> xcat[:, :1024] (pitch 2048, f16), +b1
// MODE 1: A=xcat  (K=2048) -> h (pitch 1024, f16), +b2, SiLU
// MODE 2: A=h     (K=1024) -> d_out scattered via perm (f32), +b3
template <int K, int MODE>
__global__ __launch_bounds__(256, 2) void mfma_gemm(
    const f16* __restrict__ A, const f16* __restrict__ Wt,
    const float* __restrict__ Bias, const int* __restrict__ perm,
    const int* __restrict__ cat_off, const int* __restrict__ tmap,
    void* __restrict__ OutV) {
  constexpr int PA = (MODE == 0) ? 64 : (MODE == 1) ? 2048 : 1024;
  constexpr int BK = 64;
  constexpr int NT = K / BK;

  const int nslots = tmap[0];
  if ((int)blockIdx.y >= nslots) return;
  const int ent = tmap[1 + blockIdx.y];
  const int c = ent >> 20, m0 = ent & 0xFFF;
  const int g0 = cat_off[c], cnt = cat_off[c + 1] - g0;
  const int n0 = blockIdx.x * 128;

  __shared__ f16 As[3][64 * BK];   // 3 x 8 KiB,  row pitch 64 f16 = 8 slots
  __shared__ f16 Bs[3][128 * BK];  // 3 x 16 KiB
  __shared__ int rows[64];

  const int tid = threadIdx.x;
  const int lane = tid & 63, wid = tid >> 6;
  const int wm = wid >> 1, wn = wid & 1;
  const int fr = lane & 15, fq = lane >> 4;

  if (MODE == 2 && tid < 64) {
    int m = m0 + tid;
    if (m > cnt - 1) m = cnt - 1;
    rows[tid] = perm[g0 + m];
  }

  const f16* Abase = A + (size_t)(g0 + m0) * PA;
  const f16* Bbase = Wt + ((size_t)c * HID + n0) * K;

  // Staging: linear LDS dest (slot s = 16B), global src inverse-swizzled:
  // slot (row, q) holds global k-chunk q^(row&7).  A: 512 slots, B: 1024.
#define STAGE(buf, kt)                                                        \
  do {                                                                        \
    _Pragma("unroll") for (int i_ = 0; i_ < 2; ++i_) {                        \
      const int s_ = tid + i_ * 256;                                          \
      const int r_ = s_ >> 3, qg_ = (s_ & 7) ^ (r_ & 7);                      \
      GLDS16(Abase + (size_t)r_ * PA + (kt) + qg_ * 8, &As[buf][s_ * 8]);     \
    }                                                                         \
    _Pragma("unroll") for (int i_ = 0; i_ < 4; ++i_) {                        \
      const int s_ = tid + i_ * 256;                                          \
      const int r_ = s_ >> 3, qg_ = (s_ & 7) ^ (r_ & 7);                      \
      GLDS16(Bbase + (size_t)r_ * K + (kt) + qg_ * 8, &Bs[buf][s_ * 8]);      \
    }                                                                         \
  } while (0)

  f32x4 acc[2][4];
#pragma unroll
  for (int i = 0; i < 2; ++i)
#pragma unroll
    for (int j = 0; j < 4; ++j) acc[i][j] = (f32x4){0.f, 0.f, 0.f, 0.f};

  STAGE(0, 0);
  if (NT > 1) STAGE(1, BK);

  for (int t = 0; t < NT; ++t) {
    // counted vmcnt: 6 loads/stage; steady state keeps next stage in flight
    if (t + 1 < NT) { WAITV(6); } else { WAITV(0); }
    __builtin_amdgcn_s_barrier();
    const int cur = t % 3;

    f16x8 af[2][2], bf[2][4];
#pragma unroll
    for (int ks = 0; ks < 2; ++ks) {
      const int q = ks * 4 + fq;
#pragma unroll
      for (int i = 0; i < 2; ++i) {
        const int r = wm * 32 + i * 16 + fr;
        af[ks][i] = *(const f16x8*)&As[cur][r * 64 + ((q ^ (r & 7)) * 8)];
      }
#pragma unroll
      for (int j = 0; j < 4; ++j) {
        const int r = wn * 64 + j * 16 + fr;
        bf[ks][j] = *(const f16x8*)&Bs[cur][r * 64 + ((q ^ (r & 7)) * 8)];
      }
    }
#pragma unroll
    for (int ks = 0; ks < 2; ++ks)
#pragma unroll
      for (int i = 0; i < 2; ++i)
#pragma unroll
        for (int j = 0; j < 4; ++j)
          acc[i][j] = __builtin_amdgcn_mfma_f32_16x16x32_f16(af[ks][i], bf[ks][j],
                                                             acc[i][j], 0, 0, 0);
    // issue stage t+2 AFTER the barrier that proved buf[(t-1)%3] was consumed
    if (t + 2 < NT) STAGE((t + 2) % 3, (t + 2) * BK);
  }
#undef STAGE

#pragma unroll
  for (int i = 0; i < 2; ++i) {
    const int mlb = wm * 32 + i * 16 + fq * 4;
#pragma unroll
    for (int j = 0; j < 4; ++j) {
      const int col = wn * 64 + j * 16 + fr;  // C/D: col=lane&15, row=fq*4+q
      const float bb = Bias[c * HID + n0 + col];
#pragma unroll
      for (int q = 0; q < 4; ++q) {
        const int ml = mlb + q;
        if (m0 + ml >= cnt) continue;
        float v = acc[i][j][q] + bb;
        if (MODE == 1) v = v / (1.0f + __expf(-v));
        if (MODE == 2) {
          ((float*)OutV)[(size_t)rows[ml] * HID + n0 + col] = v;
        } else if (MODE == 1) {
          ((f16*)OutV)[(size_t)(g0 + m0 + ml) * HID + n0 + col] = (f16)v;
        } else {
          ((f16*)OutV)[(size_t)(g0 + m0 + ml) * 2048 + n0 + col] = (f16)v;
        }
      }
    }
  }
}

extern "C" void kernel_launch(void* const* d_in, const int* in_sizes, int n_in,
                              void* d_out, int out_size, void* d_ws, size_t ws_size,
                              hipStream_t stream) {
  const float* actions   = (const float*)d_in[0];
  const int*   timesteps = (const int*)d_in[1];
  const int*   cat_ids   = (const int*)d_in[2];
  const float* W1 = (const float*)d_in[3];
  const float* b1 = (const float*)d_in[4];
  const float* W2 = (const float*)d_in[5];
  const float* b2 = (const float*)d_in[6];
  const float* W3 = (const float*)d_in[7];
  const float* b3 = (const float*)d_in[8];
  float* out = (float*)d_out;

  char* ws = (char*)d_ws;
  const size_t MiB = 1u << 20;
  int* perm    = (int*)(ws + 0);                       // 16 KiB
  int* cat_off = (int*)(ws + (16u << 10));             // 64 B
  int* tmap    = (int*)(ws + (20u << 10));             // 512 B
  f16* tau16   = (f16*)(ws + (32u << 10));             // 256 KiB
  f16* act_g   = (f16*)(ws + (512u << 10));            // 528 KiB (MPAD x 64)
  f16* Wt1     = (f16*)(ws + 2 * MiB);                 // 1 MiB
  f16* xcat    = (f16*)(ws + 3 * MiB);                 // 16.5 MiB (MPAD x 2048)
  f16* h       = (f16*)(ws + 20 * MiB);                // 8.25 MiB (MPAD x 1024)
  f16* Wt2     = (f16*)(ws + 29 * MiB);                // 32 MiB
  f16* Wt3     = (f16*)(ws + 61 * MiB);                // 16 MiB -> ends 77 MiB

  build_perm_kernel<<<1, 256, 0, stream>>>(cat_ids, perm, cat_off, tmap);
  tau16_kernel<<<128, 256, 0, stream>>>(timesteps, tau16);
  gather_kernel<<<NTOK, 128, 0, stream>>>(actions, tau16, perm, act_g, xcat);

  wcvt_kernel<<<dim3(HID / 64, 1, NC), 256, 0, stream>>>(W1, Wt1, 64);
  wcvt_kernel<<<dim3(HID / 64, 32, NC), 256, 0, stream>>>(W2, Wt2, 2048);
  wcvt_kernel<<<dim3(HID / 64, 16, NC), 256, 0, stream>>>(W3, Wt3, 1024);

  // y = max tile slots: sum ceil(cnt_c/64) <= 64 + 7 = 71 -> 72
  dim3 ggrid(HID / 128, 72, 1);
  mfma_gemm<64, 0><<<ggrid, 256, 0, stream>>>(act_g, Wt1, b1, perm, cat_off, tmap, xcat);
  mfma_gemm<2048, 1><<<ggrid, 256, 0, stream>>>(xcat, Wt2, b2, perm, cat_off, tmap, h);
  mfma_gemm<1024, 2><<<ggrid, 256, 0, stream>>>(h, Wt3, b3, perm, cat_off, tmap, out);
}

// Round 5
// 258.067 us; speedup vs baseline: 2.4517x; 1.0153x over previous
//
#include <hip/hip_runtime.h>
#include <cmath>

// FlowmatchingActionHead forward — fp16 MFMA, fp32 accumulate.
// R5: BM=64 BN=64 BK=32 (24KB LDS -> up to 6 blocks/CU), 1152 blocks,
// 3-deep staging with counted vmcnt, pair-XOR bank swizzle (conflict-free),
// wave-tile 16x64 (acc[1][4]).

#define NTOK 4096
#define HID  1024
#define NC   8
#define MPAD 4224  // grouped rows padded so tile staging never reads OOB

typedef _Float16 f16;
typedef _Float16 f16x8 __attribute__((ext_vector_type(8)));
typedef float    f32x4 __attribute__((ext_vector_type(4)));

#define GLDS16(g, l) __builtin_amdgcn_global_load_lds(                      \
    (const __attribute__((address_space(1))) void*)(g),                     \
    (__attribute__((address_space(3))) void*)(l), 16, 0, 0)
#define WAITV(n) asm volatile("s_waitcnt vmcnt(" #n ")" ::: "memory")

// 16B-slot index for (row r, k-chunk q) in a [R][32] f16 tile.
// Two consecutive rows form a 128B stripe of 8 slots; XOR by stripe id
// spreads each (parity,q) class over all 8 slots -> conflict-free reads.
__device__ __forceinline__ int slot16(int r, int q) {
  return (r >> 1) * 8 + ((((r & 1) << 2) | q) ^ ((r >> 1) & 7));
}

__global__ void build_perm_kernel(const int* __restrict__ cat,
                                  int* __restrict__ perm,
                                  int* __restrict__ cat_off,
                                  int* __restrict__ tmap) {
  __shared__ int cnt[NC];
  __shared__ int off[NC + 1];
  const int tid = threadIdx.x;
  if (tid < NC) cnt[tid] = 0;
  __syncthreads();
  for (int n = tid; n < NTOK; n += blockDim.x) atomicAdd(&cnt[cat[n]], 1);
  __syncthreads();
  if (tid == 0) {
    int s = 0;
    for (int c = 0; c < NC; ++c) { off[c] = s; s += cnt[c]; }
    off[NC] = s;
    int ns = 0;
    for (int c = 0; c < NC; ++c) {
      const int n = off[c + 1] - off[c];
      for (int m0 = 0; m0 < n; m0 += 64) tmap[1 + ns++] = (c << 20) | m0;
    }
    tmap[0] = ns;
  }
  __syncthreads();
  if (tid < NC) cnt[tid] = off[tid];
  if (tid <= NC) cat_off[tid] = off[tid];
  __syncthreads();
  for (int n = tid; n < NTOK; n += blockDim.x) {
    int pos = atomicAdd(&cnt[cat[n]], 1);
    perm[pos] = n;
  }
}

// tau16[b][2i]=sin(t*div_i), [2i+1]=cos; div_i=exp(i * -ln(1e4)/512)
__global__ void tau16_kernel(const int* __restrict__ ts, f16* __restrict__ tau) {
  const int b = blockIdx.x;
  const float t = (float)ts[b];
  const float cdiv = -0.017988946039015984f;  // -log(10000.0)/512
  for (int i = threadIdx.x; i < HID / 2; i += blockDim.x) {
    float ang = t * expf(cdiv * (float)i);
    tau[(size_t)b * HID + 2 * i]     = (f16)sinf(ang);
    tau[(size_t)b * HID + 2 * i + 1] = (f16)cosf(ang);
  }
}

// Per grouped row r: gather actions -> act_g (fp16) and tau row -> xcat[:,1024:]
__global__ void gather_kernel(const float* __restrict__ actions,
                              const f16* __restrict__ tau,
                              const int* __restrict__ perm,
                              f16* __restrict__ act_g, f16* __restrict__ xcat) {
  const int r = blockIdx.x;
  const int tok = perm[r];
  const int t = threadIdx.x;  // 128 threads
  if (t < 64) act_g[(size_t)r * 64 + t] = (f16)actions[(size_t)tok * 64 + t];
  const uint4* src = (const uint4*)(tau + (size_t)(tok & 127) * HID);
  uint4* dst = (uint4*)(xcat + (size_t)r * 2048 + HID);
  dst[t] = src[t];  // 128 x 16B = 1024 fp16
}

// W (NC,K,HID) f32 -> Wt (NC,HID,K) f16, 64x64 LDS-tiled transpose
__global__ __launch_bounds__(256) void wcvt_kernel(const float* __restrict__ W,
                                                   f16* __restrict__ Wt, int K) {
  const int c = blockIdx.z, k0 = blockIdx.y * 64, n0 = blockIdx.x * 64;
  __shared__ f16 tl[64][68];
  const int tid = threadIdx.x;
  const int rr = tid >> 4, cs = (tid & 15) * 4;
  const float* src = W + ((size_t)c * K + k0) * HID + n0;
#pragma unroll
  for (int it = 0; it < 4; ++it) {
    const int kr = rr + it * 16;
    float4 v = *(const float4*)(src + (size_t)kr * HID + cs);
    tl[kr][cs + 0] = (f16)v.x;
    tl[kr][cs + 1] = (f16)v.y;
    tl[kr][cs + 2] = (f16)v.z;
    tl[kr][cs + 3] = (f16)v.w;
  }
  __syncthreads();
  f16* dst = Wt + ((size_t)c * HID + n0) * K + k0;
#pragma unroll
  for (int it = 0; it < 4; ++it) {
    const int nr = rr + it * 16;
    union { f16 h[4]; uint2 u; } pk;
    pk.h[0] = tl[cs + 0][nr];
    pk.h[1] = tl[cs + 1][nr];
    pk.h[2] = tl[cs + 2][nr];
    pk.h[3] = tl[cs + 3][nr];
    *(uint2*)(dst + (size_t)nr * K + cs) = pk.u;
  }
}

// Tile: BM=64, BN=64, BK=32. 4 waves, wave-tile 16x64 (wm=wid).
// MODE 0: A=act_g (K=64)   -> xcat[:, :1024] (pitch 2048, f16), +b1
// MODE 1: A=xcat  (K=2048) -> h (pitch 1024, f16), +b2, SiLU
// MODE 2: A=h     (K=1024) -> d_out scattered via perm (f32), +b3
template <int K, int MODE>
__global__ __launch_bounds__(256, 4) void mfma_gemm(
    const f16* __restrict__ A, const f16* __restrict__ Wt,
    const float* __restrict__ Bias, const int* __restrict__ perm,
    const int* __restrict__ cat_off, const int* __restrict__ tmap,
    void* __restrict__ OutV) {
  constexpr int PA = (MODE == 0) ? 64 : (MODE == 1) ? 2048 : 1024;
  constexpr int BK = 32;
  constexpr int NT = K / BK;

  const int nslots = tmap[0];
  if ((int)blockIdx.y >= nslots) return;
  const int ent = tmap[1 + blockIdx.y];
  const int c = ent >> 20, m0 = ent & 0xFFF;
  const int g0 = cat_off[c], cnt = cat_off[c + 1] - g0;
  const int n0 = blockIdx.x * 64;

  __shared__ f16 As[3][64 * BK];  // 3 x 4 KiB
  __shared__ f16 Bs[3][64 * BK];  // 3 x 4 KiB
  __shared__ int rows[64];

  const int tid = threadIdx.x;
  const int lane = tid & 63, wid = tid >> 6;
  const int fr = lane & 15, fq = lane >> 4;  // fragment row / k-chunk

  if (MODE == 2 && tid < 64) {
    int m = m0 + tid;
    if (m > cnt - 1) m = cnt - 1;
    rows[tid] = perm[g0 + m];
  }

  const f16* Abase = A + (size_t)(g0 + m0) * PA;
  const f16* Bbase = Wt + ((size_t)c * HID + n0) * K;

  // Each thread stages one 16B slot of A and one of B per K-step.
  // LDS dest linear (slot tid); global source inverse-swizzled (rule 21).
  const int pr_ = tid >> 3, u_ = tid & 7, w_ = u_ ^ (pr_ & 7);
  const int sr_ = 2 * pr_ + (w_ >> 2), sq_ = (w_ & 3) * 8;
#define STAGE(buf, kt)                                                   \
  do {                                                                   \
    GLDS16(Abase + (size_t)sr_ * PA + (kt) + sq_, &As[buf][tid * 8]);    \
    GLDS16(Bbase + (size_t)sr_ * K + (kt) + sq_, &Bs[buf][tid * 8]);     \
  } while (0)

  f32x4 acc[4];
#pragma unroll
  for (int j = 0; j < 4; ++j) acc[j] = (f32x4){0.f, 0.f, 0.f, 0.f};

  STAGE(0, 0);
  if (NT > 1) STAGE(1, BK);

  for (int t = 0; t < NT; ++t) {
    if (t + 1 < NT) { WAITV(2); } else { WAITV(0); }  // counted: next stage stays in flight
    __builtin_amdgcn_s_barrier();
    const int cur = t % 3;

    const int ar = wid * 16 + fr;
    f16x8 af = *(const f16x8*)&As[cur][slot16(ar, fq) * 8];
    f16x8 bf[4];
#pragma unroll
    for (int j = 0; j < 4; ++j) {
      const int br = j * 16 + fr;
      bf[j] = *(const f16x8*)&Bs[cur][slot16(br, fq) * 8];
    }
#pragma unroll
    for (int j = 0; j < 4; ++j)
      acc[j] = __builtin_amdgcn_mfma_f32_16x16x32_f16(af, bf[j], acc[j], 0, 0, 0);
    if (t + 2 < NT) STAGE((t + 2) % 3, (t + 2) * BK);  // after barrier: buf[(t-1)%3] free
  }
#undef STAGE

  const int mlb = wid * 16 + fq * 4;
#pragma unroll
  for (int j = 0; j < 4; ++j) {
    const int col = j * 16 + fr;  // C/D: col=lane&15, row=fq*4+q
    const float bb = Bias[c * HID + n0 + col];
#pragma unroll
    for (int q = 0; q < 4; ++q) {
      const int ml = mlb + q;
      if (m0 + ml >= cnt) continue;
      float v = acc[j][q] + bb;
      if (MODE == 1) v = v / (1.0f + __expf(-v));
      if (MODE == 2) {
        ((float*)OutV)[(size_t)rows[ml] * HID + n0 + col] = v;
      } else if (MODE == 1) {
        ((f16*)OutV)[(size_t)(g0 + m0 + ml) * HID + n0 + col] = (f16)v;
      } else {
        ((f16*)OutV)[(size_t)(g0 + m0 + ml) * 2048 + n0 + col] = (f16)v;
      }
    }
  }
}

extern "C" void kernel_launch(void* const* d_in, const int* in_sizes, int n_in,
                              void* d_out, int out_size, void* d_ws, size_t ws_size,
                              hipStream_t stream) {
  const float* actions   = (const float*)d_in[0];
  const int*   timesteps = (const int*)d_in[1];
  const int*   cat_ids   = (const int*)d_in[2];
  const float* W1 = (const float*)d_in[3];
  const float* b1 = (const float*)d_in[4];
  const float* W2 = (const float*)d_in[5];
  const float* b2 = (const float*)d_in[6];
  const float* W3 = (const float*)d_in[7];
  const float* b3 = (const float*)d_in[8];
  float* out = (float*)d_out;

  char* ws = (char*)d_ws;
  const size_t MiB = 1u << 20;
  int* perm    = (int*)(ws + 0);                       // 16 KiB
  int* cat_off = (int*)(ws + (16u << 10));             // 64 B
  int* tmap    = (int*)(ws + (20u << 10));             // 512 B
  f16* tau16   = (f16*)(ws + (32u << 10));             // 256 KiB
  f16* act_g   = (f16*)(ws + (512u << 10));            // 528 KiB (MPAD x 64)
  f16* Wt1     = (f16*)(ws + 2 * MiB);                 // 1 MiB
  f16* xcat    = (f16*)(ws + 3 * MiB);                 // 16.5 MiB (MPAD x 2048)
  f16* h       = (f16*)(ws + 20 * MiB);                // 8.25 MiB (MPAD x 1024)
  f16* Wt2     = (f16*)(ws + 29 * MiB);                // 32 MiB
  f16* Wt3     = (f16*)(ws + 61 * MiB);                // 16 MiB -> ends 77 MiB

  build_perm_kernel<<<1, 1024, 0, stream>>>(cat_ids, perm, cat_off, tmap);
  tau16_kernel<<<128, 256, 0, stream>>>(timesteps, tau16);
  gather_kernel<<<NTOK, 128, 0, stream>>>(actions, tau16, perm, act_g, xcat);

  wcvt_kernel<<<dim3(HID / 64, 1, NC), 256, 0, stream>>>(W1, Wt1, 64);
  wcvt_kernel<<<dim3(HID / 64, 32, NC), 256, 0, stream>>>(W2, Wt2, 2048);
  wcvt_kernel<<<dim3(HID / 64, 16, NC), 256, 0, stream>>>(W3, Wt3, 1024);

  // y = max tile slots: sum ceil(cnt_c/64) <= 64 + 7 = 71 -> 72
  dim3 ggrid(HID / 64, 72, 1);
  mfma_gemm<64, 0><<<ggrid, 256, 0, stream>>>(act_g, Wt1, b1, perm, cat_off, tmap, xcat);
  mfma_gemm<2048, 1><<<ggrid, 256, 0, stream>>>(xcat, Wt2, b2, perm, cat_off, tmap, h);
  mfma_gemm<1024, 2><<<ggrid, 256, 0, stream>>>(h, Wt3, b3, perm, cat_off, tmap, out);
}

// Round 9
// 245.007 us; speedup vs baseline: 2.5824x; 1.0533x over previous
//
#include <hip/hip_runtime.h>
#include <cmath>

// FlowmatchingActionHead forward — fp16 MFMA with algebraic collapse.
// aemb@W2top = act@(W1c@W2top)+b1c@W2top  -> W12t[c] (1024x64) precomputed
// tau@W2bot has 128 distinct rows         -> ttau[c][128][1024] precomputed
// Main pass: L2PRE (K=64) -> silu -> L3 (K=1024). 9.1 GF vs original 26.3.
// GEMMs: BM=BN=64, BK=32, 4 waves, ring-4 LDS staging, counted vmcnt,
// pair-XOR bank swizzle (R5-verified machinery).
// (R9 = R6 resubmitted verbatim; R6/R7/R8 were infra failures; desk-check clean.)

#define NTOK 4096
#define HID  1024
#define NC   8
#define MPAD 4224

typedef _Float16 f16;
typedef _Float16 f16x8 __attribute__((ext_vector_type(8)));
typedef float    f32x4 __attribute__((ext_vector_type(4)));

#define GLDS16(g, l) __builtin_amdgcn_global_load_lds(                      \
    (const __attribute__((address_space(1))) void*)(g),                     \
    (__attribute__((address_space(3))) void*)(l), 16, 0, 0)
#define WAITV(n) asm volatile("s_waitcnt vmcnt(" #n ")" ::: "memory")

// 16B-slot index for (row r, k-chunk q) in a [R][32] f16 tile (R5-verified).
__device__ __forceinline__ int slot16(int r, int q) {
  return (r >> 1) * 8 + ((((r & 1) << 2) | q) ^ ((r >> 1) & 7));
}

__global__ void build_perm_kernel(const int* __restrict__ cat,
                                  int* __restrict__ perm,
                                  int* __restrict__ cat_off,
                                  int* __restrict__ tmap) {
  __shared__ int cnt[NC];
  __shared__ int off[NC + 1];
  const int tid = threadIdx.x;
  if (tid < NC) cnt[tid] = 0;
  __syncthreads();
  for (int n = tid; n < NTOK; n += blockDim.x) atomicAdd(&cnt[cat[n]], 1);
  __syncthreads();
  if (tid == 0) {
    int s = 0;
    for (int c = 0; c < NC; ++c) { off[c] = s; s += cnt[c]; }
    off[NC] = s;
    int ns = 0;
    for (int c = 0; c < NC; ++c) {
      const int n = off[c + 1] - off[c];
      for (int m0 = 0; m0 < n; m0 += 64) tmap[1 + ns++] = (c << 20) | m0;
    }
    tmap[0] = ns;
  }
  __syncthreads();
  if (tid < NC) cnt[tid] = off[tid];
  if (tid <= NC) cat_off[tid] = off[tid];
  __syncthreads();
  for (int n = tid; n < NTOK; n += blockDim.x) {
    int pos = atomicAdd(&cnt[cat[n]], 1);
    perm[pos] = n;
  }
}

__global__ void tau16_kernel(const int* __restrict__ ts, f16* __restrict__ tau) {
  const int b = blockIdx.x;
  const float t = (float)ts[b];
  const float cdiv = -0.017988946039015984f;  // -log(10000)/512
  for (int i = threadIdx.x; i < HID / 2; i += blockDim.x) {
    float ang = t * expf(cdiv * (float)i);
    tau[(size_t)b * HID + 2 * i]     = (f16)sinf(ang);
    tau[(size_t)b * HID + 2 * i + 1] = (f16)cosf(ang);
  }
}

__global__ void gather_kernel(const float* __restrict__ actions,
                              const int* __restrict__ perm,
                              f16* __restrict__ act_g) {
  const int r = blockIdx.x;
  const int tok = perm[r];
  act_g[(size_t)r * 64 + threadIdx.x] =
      (f16)actions[(size_t)tok * 64 + threadIdx.x];
}

// W1 (8,64,1024) f32 -> f16, linear
__global__ void w1cvt_kernel(const float* __restrict__ W1, f16* __restrict__ o) {
  const int i = blockIdx.x * 256 + threadIdx.x;  // 131072 float4s
  float4 v = *(const float4*)(W1 + (size_t)i * 4);
  union { f16 h[4]; uint2 u; } pk;
  pk.h[0] = (f16)v.x; pk.h[1] = (f16)v.y; pk.h[2] = (f16)v.z; pk.h[3] = (f16)v.w;
  *(uint2*)(o + (size_t)i * 4) = pk.u;
}

// W (NC,K,HID) f32 -> Wt (NC,HID,K) f16 (verified R3-R5)
__global__ __launch_bounds__(256) void wcvt_kernel(const float* __restrict__ W,
                                                   f16* __restrict__ Wt, int K) {
  const int c = blockIdx.z, k0 = blockIdx.y * 64, n0 = blockIdx.x * 64;
  __shared__ f16 tl[64][68];
  const int tid = threadIdx.x;
  const int rr = tid >> 4, cs = (tid & 15) * 4;
  const float* src = W + ((size_t)c * K + k0) * HID + n0;
#pragma unroll
  for (int it = 0; it < 4; ++it) {
    const int kr = rr + it * 16;
    float4 v = *(const float4*)(src + (size_t)kr * HID + cs);
    tl[kr][cs + 0] = (f16)v.x;
    tl[kr][cs + 1] = (f16)v.y;
    tl[kr][cs + 2] = (f16)v.z;
    tl[kr][cs + 3] = (f16)v.w;
  }
  __syncthreads();
  f16* dst = Wt + ((size_t)c * HID + n0) * K + k0;
#pragma unroll
  for (int it = 0; it < 4; ++it) {
    const int nr = rr + it * 16;
    union { f16 h[4]; uint2 u; } pk;
    pk.h[0] = tl[cs + 0][nr];
    pk.h[1] = tl[cs + 1][nr];
    pk.h[2] = tl[cs + 2][nr];
    pk.h[3] = tl[cs + 3][nr];
    *(uint2*)(dst + (size_t)nr * K + cs) = pk.u;
  }
}

// bias2eff[c][o] = b1[c] . Wt2[c][o][0:1024] + b2[c][o]   (wave per o)
__global__ __launch_bounds__(256) void bias2eff_kernel(
    const float* __restrict__ b1, const float* __restrict__ b2,
    const f16* __restrict__ Wt2, float* __restrict__ out) {
  const int c = blockIdx.y;
  const int o = blockIdx.x * 4 + (threadIdx.x >> 6);
  const int lane = threadIdx.x & 63;
  const float* bp = b1 + c * HID + lane * 16;
  const f16* wp = Wt2 + ((size_t)c * HID + o) * 2048 + lane * 16;
  float s = 0.f;
#pragma unroll
  for (int u = 0; u < 4; ++u) {
    float4 bv = *(const float4*)(bp + u * 4);
    f16 w0 = wp[u * 4 + 0], w1 = wp[u * 4 + 1], w2 = wp[u * 4 + 2], w3 = wp[u * 4 + 3];
    s += bv.x * (float)w0 + bv.y * (float)w1 + bv.z * (float)w2 + bv.w * (float)w3;
  }
#pragma unroll
  for (int off = 32; off >= 1; off >>= 1) s += __shfl_down(s, off);
  if (lane == 0) out[c * HID + o] = s + b2[c * HID + o];
}

// Unified MFMA GEMM. BM=BN=64, BK=32, 4 waves, ring-4, counted vmcnt.
// MODE 0 (W12T): A=Wt2 top (PA=2048,K=1024), B=w1f16 (PB=1024), out W12t f16 (pitch 64)
// MODE 1 (TTAU): A=tau16 (PA=1024), B=Wt2 bot (+1024, PB=2048), bias=bias2eff, out ttau f32
// MODE 2 (L2PRE): A=act_g (PA=64,K=64), B=W12t (PB=64), +ttau row +silu, out h f16
// MODE 3 (L3):   A=h (PA=1024), B=Wt3 (PB=1024), +b3, scatter out f32
template <int K, int PA, int PB, int MODE>
__global__ __launch_bounds__(256, 4) void mfma_gemm(
    const f16* __restrict__ A, const f16* __restrict__ B,
    const float* __restrict__ Bias, const float* __restrict__ Ttau,
    const int* __restrict__ perm, const int* __restrict__ cat_off,
    const int* __restrict__ tmap, void* __restrict__ OutV) {
  constexpr int BK = 32;
  constexpr int NT = K / BK;

  int c, m0, g0 = 0, cnt, n0;
  if constexpr (MODE == 0) {
    c = blockIdx.y >> 4; m0 = (blockIdx.y & 15) * 64; cnt = 1024; n0 = 0;
  } else if constexpr (MODE == 1) {
    c = blockIdx.y >> 1; m0 = (blockIdx.y & 1) * 64; cnt = 128;
    n0 = blockIdx.x * 64;
  } else {
    const int nslots = tmap[0];
    if ((int)blockIdx.y >= nslots) return;
    const int ent = tmap[1 + blockIdx.y];
    c = ent >> 20; m0 = ent & 0xFFF;
    g0 = cat_off[c]; cnt = cat_off[c + 1] - g0;
    n0 = blockIdx.x * 64;
  }

  __shared__ f16 As[4][64 * BK];
  __shared__ f16 Bs[4][64 * BK];
  __shared__ int rows[64];

  const int tid = threadIdx.x;
  const int lane = tid & 63, wid = tid >> 6;
  const int fr = lane & 15, fq = lane >> 4;

  if (MODE >= 2 && tid < 64) {
    int m = m0 + tid;
    if (m > cnt - 1) m = cnt - 1;
    rows[tid] = perm[g0 + m];
  }

  const f16* Abase;
  const f16* Bbase;
  if constexpr (MODE == 0) {
    Abase = A + ((size_t)c * 1024 + m0) * 2048;
    Bbase = B + (size_t)c * 65536;
  } else if constexpr (MODE == 1) {
    Abase = A + (size_t)m0 * 1024;
    Bbase = B + ((size_t)c * 1024 + n0) * 2048 + 1024;
  } else if constexpr (MODE == 2) {
    Abase = A + (size_t)(g0 + m0) * 64;
    Bbase = B + (size_t)c * 65536 + (size_t)n0 * 64;
  } else {
    Abase = A + (size_t)(g0 + m0) * 1024;
    Bbase = B + ((size_t)c * 1024 + n0) * 1024;
  }

  // inverse-swizzled global source, linear LDS dest (R5-verified)
  const int pr_ = tid >> 3, u_ = tid & 7, w_ = u_ ^ (pr_ & 7);
  const int sr_ = 2 * pr_ + (w_ >> 2), sq_ = (w_ & 3) * 8;
#define STAGE(buf, kt)                                                   \
  do {                                                                   \
    GLDS16(Abase + (size_t)sr_ * PA + (kt) + sq_, &As[buf][tid * 8]);    \
    GLDS16(Bbase + (size_t)sr_ * PB + (kt) + sq_, &Bs[buf][tid * 8]);    \
  } while (0)

  f32x4 acc[4];
#pragma unroll
  for (int j = 0; j < 4; ++j) acc[j] = (f32x4){0.f, 0.f, 0.f, 0.f};

  STAGE(0, 0);
  if (NT > 1) STAGE(1, BK);
  if (NT > 2) STAGE(2, 2 * BK);

  for (int t = 0; t < NT; ++t) {
    if (t + 2 < NT) { WAITV(4); }        // stages t+1,t+2 stay in flight
    else if (t + 1 < NT) { WAITV(2); }
    else { WAITV(0); }
    __builtin_amdgcn_s_barrier();
    const int cur = t & 3;

    const int ar = wid * 16 + fr;
    f16x8 af = *(const f16x8*)&As[cur][slot16(ar, fq) * 8];
    f16x8 bf[4];
#pragma unroll
    for (int j = 0; j < 4; ++j)
      bf[j] = *(const f16x8*)&Bs[cur][slot16(j * 16 + fr, fq) * 8];
#pragma unroll
    for (int j = 0; j < 4; ++j)
      acc[j] = __builtin_amdgcn_mfma_f32_16x16x32_f16(af, bf[j], acc[j], 0, 0, 0);
    if (t + 3 < NT) STAGE((t + 3) & 3, (t + 3) * BK);  // ring-4: buf (t-1)&3 free
  }
#undef STAGE

  const int mlb = wid * 16 + fq * 4;
#pragma unroll
  for (int j = 0; j < 4; ++j) {
    const int col = j * 16 + fr;  // C/D: col=lane&15, row=fq*4+q
#pragma unroll
    for (int q = 0; q < 4; ++q) {
      const int ml = mlb + q;
      const int m = m0 + ml;
      if constexpr (MODE == 0) {
        ((f16*)OutV)[(size_t)c * 65536 + (size_t)m * 64 + col] = (f16)acc[j][q];
      } else if constexpr (MODE == 1) {
        float v = acc[j][q] + Bias[c * HID + n0 + col];
        ((float*)OutV)[(size_t)c * 131072 + (size_t)m * 1024 + n0 + col] = v;
      } else if constexpr (MODE == 2) {
        if (m >= cnt) continue;
        const int b = rows[ml] & 127;
        float v = acc[j][q] + Ttau[((size_t)c * 128 + b) * 1024 + n0 + col];
        v = v / (1.0f + __expf(-v));
        ((f16*)OutV)[(size_t)(g0 + m) * 1024 + n0 + col] = (f16)v;
      } else {
        if (m >= cnt) continue;
        float v = acc[j][q] + Bias[c * HID + n0 + col];
        ((float*)OutV)[(size_t)rows[ml] * 1024 + n0 + col] = v;
      }
    }
  }
}

extern "C" void kernel_launch(void* const* d_in, const int* in_sizes, int n_in,
                              void* d_out, int out_size, void* d_ws, size_t ws_size,
                              hipStream_t stream) {
  const float* actions   = (const float*)d_in[0];
  const int*   timesteps = (const int*)d_in[1];
  const int*   cat_ids   = (const int*)d_in[2];
  const float* W1 = (const float*)d_in[3];
  const float* b1 = (const float*)d_in[4];
  const float* W2 = (const float*)d_in[5];
  const float* b2 = (const float*)d_in[6];
  const float* W3 = (const float*)d_in[7];
  const float* b3 = (const float*)d_in[8];
  float* out = (float*)d_out;

  char* ws = (char*)d_ws;
  const size_t MiB = 1u << 20;
  int*   perm    = (int*)(ws + 0);                 // 16 KiB
  int*   cat_off = (int*)(ws + (16u << 10));       // 64 B
  int*   tmap    = (int*)(ws + (20u << 10));       // 512 B
  f16*   tau16   = (f16*)(ws + (32u << 10));       // 256 KiB (128x1024)
  f16*   act_g   = (f16*)(ws + (512u << 10));      // 528 KiB (MPADx64)
  f16*   w1f16   = (f16*)(ws + 2 * MiB);           // 1 MiB (8,64,1024)
  f16*   W12t    = (f16*)(ws + 3 * MiB);           // 1 MiB (8,1024,64)
  float* b2eff   = (float*)(ws + 4 * MiB);         // 32 KiB (8,1024)
  float* ttau    = (float*)(ws + 5 * MiB);         // 4 MiB (8,128,1024)
  f16*   h       = (f16*)(ws + 9 * MiB);           // 8.25 MiB (MPADx1024)
  f16*   Wt2     = (f16*)(ws + 18 * MiB);          // 32 MiB (8,1024,2048)
  f16*   Wt3     = (f16*)(ws + 50 * MiB);          // 16 MiB (8,1024,1024) -> 66 MiB

  build_perm_kernel<<<1, 1024, 0, stream>>>(cat_ids, perm, cat_off, tmap);
  tau16_kernel<<<128, 256, 0, stream>>>(timesteps, tau16);
  gather_kernel<<<NTOK, 64, 0, stream>>>(actions, perm, act_g);
  w1cvt_kernel<<<512, 256, 0, stream>>>(W1, w1f16);
  wcvt_kernel<<<dim3(HID / 64, 32, NC), 256, 0, stream>>>(W2, Wt2, 2048);
  wcvt_kernel<<<dim3(HID / 64, 16, NC), 256, 0, stream>>>(W3, Wt3, 1024);
  bias2eff_kernel<<<dim3(256, NC), 256, 0, stream>>>(b1, b2, Wt2, b2eff);

  // W12T: per cat (1024x64) = Wt2top @ w1f16^T
  mfma_gemm<1024, 2048, 1024, 0><<<dim3(1, 128), 256, 0, stream>>>(
      Wt2, w1f16, nullptr, nullptr, nullptr, nullptr, nullptr, W12t);
  // TTAU: per cat (128x1024) = tau @ W2bot + b2eff
  mfma_gemm<1024, 1024, 2048, 1><<<dim3(16, 16), 256, 0, stream>>>(
      tau16, Wt2, b2eff, nullptr, nullptr, nullptr, nullptr, ttau);
  // L2PRE: h = silu(act_g @ W12t + ttau[row])   (K=64)
  mfma_gemm<64, 64, 64, 2><<<dim3(16, 72), 256, 0, stream>>>(
      act_g, W12t, nullptr, ttau, perm, cat_off, tmap, h);
  // L3: out = h @ Wt3 + b3, scattered
  mfma_gemm<1024, 1024, 1024, 3><<<dim3(16, 72), 256, 0, stream>>>(
      h, Wt3, b3, nullptr, perm, cat_off, tmap, out);
}